// Round 1
// baseline (794.212 us; speedup 1.0000x reference)
//
#include <hip/hip_runtime.h>
#include <hip/hip_bf16.h>

// ---------------- CSR build ----------------

__global__ __launch_bounds__(256) void k_count(const int* __restrict__ dst,
                                               int* __restrict__ cnt, int n) {
    int e = blockIdx.x * 256 + threadIdx.x;
    if (e < n) atomicAdd(&cnt[dst[e]], 1);
}

// block-wise exclusive scan (within-block), block totals to bsum
__global__ __launch_bounds__(1024) void k_scan1(const int* __restrict__ cnt,
                                                int* __restrict__ rowst,
                                                int* __restrict__ bsum, int n) {
    __shared__ int tmp[1024];
    int t = threadIdx.x;
    int i = blockIdx.x * 1024 + t;
    int v = (i < n) ? cnt[i] : 0;
    tmp[t] = v;
    __syncthreads();
    for (int off = 1; off < 1024; off <<= 1) {
        int u = 0;
        if (t >= off) u = tmp[t - off];
        __syncthreads();
        if (t >= off) tmp[t] += u;
        __syncthreads();
    }
    if (i < n) rowst[i] = tmp[t] - v;  // exclusive within block
    if (t == 1023) bsum[blockIdx.x] = tmp[1023];
}

__global__ void k_scan2(int* bsum, int nb, int* rowst, int n) {
    if (threadIdx.x == 0 && blockIdx.x == 0) {
        int c = 0;
        for (int i = 0; i < nb; ++i) { int v = bsum[i]; bsum[i] = c; c += v; }
        rowst[n] = c;
    }
}

__global__ __launch_bounds__(256) void k_scan3(const int* __restrict__ cnt,
                                               int* __restrict__ rowst,
                                               const int* __restrict__ bsum,
                                               int* __restrict__ cur,
                                               float* __restrict__ inv, int n) {
    int i = blockIdx.x * 256 + threadIdx.x;
    if (i < n) {
        int r = rowst[i] + bsum[i >> 10];
        rowst[i] = r;
        cur[i] = r;
        int c = cnt[i];
        inv[i] = 1.0f / (float)(c > 1 ? c : 1);
    }
}

__global__ __launch_bounds__(256) void k_scatter(const int* __restrict__ src,
                                                 const int* __restrict__ dst,
                                                 int* __restrict__ cur,
                                                 int* __restrict__ ssrc, int n) {
    int e = blockIdx.x * 256 + threadIdx.x;
    if (e < n) {
        int d = dst[e];
        int p = atomicAdd(&cur[d], 1);
        ssrc[p] = src[e];
    }
}

// ---------------- mean aggregation over CSR ----------------
// 8 nodes per 256-thread block; 32-lane group per node; lanes 0..24 hold float4
__global__ __launch_bounds__(256) void k_aggr(const float* __restrict__ X,
                                              const int* __restrict__ ssrc,
                                              const int* __restrict__ rowst,
                                              const float* __restrict__ inv,
                                              float* __restrict__ out, int n) {
    int g = threadIdx.x >> 5;
    int l = threadIdx.x & 31;
    int node = blockIdx.x * 8 + g;
    if (node >= n) return;
    int s = rowst[node];
    int e = rowst[node + 1];
    bool act = l < 25;
    float ax = 0.f, ay = 0.f, az = 0.f, aw = 0.f;
    int i = s;
    for (; i + 4 <= e; i += 4) {
        int s0 = ssrc[i], s1 = ssrc[i + 1], s2 = ssrc[i + 2], s3 = ssrc[i + 3];
        if (act) {
            float4 v0 = *(const float4*)&X[(size_t)s0 * 100 + l * 4];
            float4 v1 = *(const float4*)&X[(size_t)s1 * 100 + l * 4];
            float4 v2 = *(const float4*)&X[(size_t)s2 * 100 + l * 4];
            float4 v3 = *(const float4*)&X[(size_t)s3 * 100 + l * 4];
            ax += v0.x + v1.x + v2.x + v3.x;
            ay += v0.y + v1.y + v2.y + v3.y;
            az += v0.z + v1.z + v2.z + v3.z;
            aw += v0.w + v1.w + v2.w + v3.w;
        }
    }
    for (; i < e; ++i) {
        int s0 = ssrc[i];
        if (act) {
            float4 v0 = *(const float4*)&X[(size_t)s0 * 100 + l * 4];
            ax += v0.x; ay += v0.y; az += v0.z; aw += v0.w;
        }
    }
    if (act) {
        float f = inv[node];
        float4 o; o.x = ax * f; o.y = ay * f; o.z = az * f; o.w = aw * f;
        *(float4*)&out[(size_t)node * 100 + l * 4] = o;
    }
}

// ---------------- fused double-GEMM: out = act(A@Wl + X@Wr + b) ----------------
// 256 thr = 4 waves, 4 rows/wave -> 16 rows/block. W^T staged in LDS (40KB),
// two passes (Wl then Wr) so LDS stays 40KB -> 4 blocks/CU.
// NOTE: A and out may alias (in-place, same-row dependence only) -> no restrict.
__global__ __launch_bounds__(256) void k_gemm(const float* __restrict__ X,
                                              const float* A,
                                              const float* __restrict__ Wl,
                                              const float* __restrict__ Wr,
                                              const float* __restrict__ bias,
                                              float* out, int relu, int n) {
    extern __shared__ float wt[];  // 10000 floats, W^T: wt[col*100 + k]
    const int tid = threadIdx.x;
    const int lane = tid & 63;
    const int wave = tid >> 6;
    int row0 = (blockIdx.x * 4 + wave) * 4;
    row0 = __builtin_amdgcn_readfirstlane(row0);
    const int c0 = lane;
    const int c1 = lane + 64;
    const bool hc1 = (c1 < 100);
    const bool live = (row0 < n);
    const int nr = live ? ((n - row0 < 4) ? (n - row0) : 4) : 0;

    float acc0[4] = {0.f, 0.f, 0.f, 0.f};
    float acc1[4] = {0.f, 0.f, 0.f, 0.f};

    // ---- pass 1: A @ Wl ----
    for (int i = tid; i < 10000; i += 256) {
        int kk = i / 100;
        int c = i - kk * 100;
        wt[c * 100 + kk] = Wl[i];
    }
    __syncthreads();
    if (live) {
        for (int k = 0; k < 100; k += 4) {
            float4 w0 = *(const float4*)&wt[c0 * 100 + k];
            float4 w1 = hc1 ? *(const float4*)&wt[c1 * 100 + k] : make_float4(0.f, 0.f, 0.f, 0.f);
#pragma unroll
            for (int r = 0; r < 4; ++r) {
                if (r >= nr) break;
                float4 av = *(const float4*)(A + (size_t)(row0 + r) * 100 + k);
                acc0[r] += av.x * w0.x + av.y * w0.y + av.z * w0.z + av.w * w0.w;
                acc1[r] += av.x * w1.x + av.y * w1.y + av.z * w1.z + av.w * w1.w;
            }
        }
    }
    __syncthreads();
    // ---- pass 2: X @ Wr ----
    for (int i = tid; i < 10000; i += 256) {
        int kk = i / 100;
        int c = i - kk * 100;
        wt[c * 100 + kk] = Wr[i];
    }
    __syncthreads();
    if (live) {
        for (int k = 0; k < 100; k += 4) {
            float4 w0 = *(const float4*)&wt[c0 * 100 + k];
            float4 w1 = hc1 ? *(const float4*)&wt[c1 * 100 + k] : make_float4(0.f, 0.f, 0.f, 0.f);
#pragma unroll
            for (int r = 0; r < 4; ++r) {
                if (r >= nr) break;
                float4 xv = *(const float4*)(X + (size_t)(row0 + r) * 100 + k);
                acc0[r] += xv.x * w0.x + xv.y * w0.y + xv.z * w0.z + xv.w * w0.w;
                acc1[r] += xv.x * w1.x + xv.y * w1.y + xv.z * w1.z + xv.w * w1.w;
            }
        }
        float bb0 = bias[c0];
        float bb1 = hc1 ? bias[c1] : 0.f;
        for (int r = 0; r < nr; ++r) {
            float v0 = acc0[r] + bb0;
            if (relu) v0 = fmaxf(v0, 0.f);
            out[(size_t)(row0 + r) * 100 + c0] = v0;
            if (hc1) {
                float v1 = acc1[r] + bb1;
                if (relu) v1 = fmaxf(v1, 0.f);
                out[(size_t)(row0 + r) * 100 + c1] = v1;
            }
        }
    }
}

// ---------------- global mean pool + linear head ----------------
// batch is sorted: block g binary-searches its node range.
__global__ __launch_bounds__(128) void k_pool(const float* __restrict__ H,
                                              const int* __restrict__ batch,
                                              const float* __restrict__ Wlin,
                                              const float* __restrict__ blin,
                                              float* __restrict__ out, int n) {
    int g = blockIdx.x;
    int t = threadIdx.x;
    int lo = 0, hi = n;
    while (lo < hi) { int m = (lo + hi) >> 1; if (batch[m] < g) lo = m + 1; else hi = m; }
    int lo2 = lo, hi2 = n;
    while (lo2 < hi2) { int m = (lo2 + hi2) >> 1; if (batch[m] < g + 1) lo2 = m + 1; else hi2 = m; }

    __shared__ float gm[100];
    float acc = 0.f;
    if (t < 100) {
        int i = lo;
        for (; i + 2 <= lo2; i += 2)
            acc += H[(size_t)i * 100 + t] + H[(size_t)(i + 1) * 100 + t];
        if (i < lo2) acc += H[(size_t)i * 100 + t];
        float f = (lo2 > lo) ? 1.0f / (float)(lo2 - lo) : 0.0f;
        gm[t] = acc * f;
    }
    __syncthreads();
    if (t < 2) {
        float o = blin[t];
        for (int k = 0; k < 100; ++k) o += gm[k] * Wlin[k * 2 + t];
        out[g * 2 + t] = o;
    }
}

// ---------------- launch ----------------

extern "C" void kernel_launch(void* const* d_in, const int* in_sizes, int n_in,
                              void* d_out, int out_size, void* d_ws, size_t ws_size,
                              hipStream_t stream) {
    const float* x    = (const float*)d_in[0];
    const int*   ei   = (const int*)d_in[1];
    const int*   batch= (const int*)d_in[2];
    const float* W1l  = (const float*)d_in[3];
    const float* b1   = (const float*)d_in[4];
    const float* W1r  = (const float*)d_in[5];
    const float* W2l  = (const float*)d_in[6];
    const float* b2   = (const float*)d_in[7];
    const float* W2r  = (const float*)d_in[8];
    const float* W3l  = (const float*)d_in[9];
    const float* b3   = (const float*)d_in[10];
    const float* W3r  = (const float*)d_in[11];
    const float* Wlin = (const float*)d_in[12];
    const float* blin = (const float*)d_in[13];
    float* out = (float*)d_out;

    const int n_nodes  = in_sizes[0] / 100;
    const int n_edges  = in_sizes[1] / 2;
    const int n_graphs = out_size / 2;
    const int* src = ei;
    const int* dst = ei + n_edges;

    char* ws = (char*)d_ws;
    size_t o = 0;
    auto alloc = [&](size_t bytes) { size_t r = o; o = (o + bytes + 255) & ~(size_t)255; return r; };
    int*   cnt  = (int*)(ws + alloc((size_t)n_nodes * 4));
    int*   rowp = (int*)(ws + alloc((size_t)(n_nodes + 1) * 4));
    int*   cur  = (int*)(ws + alloc((size_t)n_nodes * 4));
    int*   bsum = (int*)(ws + alloc(64 * 4));
    float* inv  = (float*)(ws + alloc((size_t)n_nodes * 4));
    int*   ssrc = (int*)(ws + alloc((size_t)n_edges * 4));
    float* A    = (float*)(ws + alloc((size_t)n_nodes * 100 * 4));
    float* B    = (float*)(ws + alloc((size_t)n_nodes * 100 * 4));

    hipMemsetAsync(cnt, 0, (size_t)n_nodes * 4, stream);

    const int eb = (n_edges + 255) / 256;
    const int sb = (n_nodes + 1023) / 1024;
    k_count<<<eb, 256, 0, stream>>>(dst, cnt, n_edges);
    k_scan1<<<sb, 1024, 0, stream>>>(cnt, rowp, bsum, n_nodes);
    k_scan2<<<1, 64, 0, stream>>>(bsum, sb, rowp, n_nodes);
    k_scan3<<<(n_nodes + 255) / 256, 256, 0, stream>>>(cnt, rowp, bsum, cur, inv, n_nodes);
    k_scatter<<<eb, 256, 0, stream>>>(src, dst, cur, ssrc, n_edges);

    const int ab = (n_nodes + 7) / 8;
    const int gb = (n_nodes + 15) / 16;

    // layer 1: A = aggr(x); A = relu(A@W1l + x@W1r + b1)
    k_aggr<<<ab, 256, 0, stream>>>(x, ssrc, rowp, inv, A, n_nodes);
    k_gemm<<<gb, 256, 40000, stream>>>(x, A, W1l, W1r, b1, A, 1, n_nodes);
    // layer 2: B = aggr(A); B = relu(B@W2l*... in-place)
    k_aggr<<<ab, 256, 0, stream>>>(A, ssrc, rowp, inv, B, n_nodes);
    k_gemm<<<gb, 256, 40000, stream>>>(A, B, W2l, W2r, b2, B, 1, n_nodes);
    // layer 3 (no relu): A = aggr(B); A = B-layer out
    k_aggr<<<ab, 256, 0, stream>>>(B, ssrc, rowp, inv, A, n_nodes);
    k_gemm<<<gb, 256, 40000, stream>>>(B, A, W3l, W3r, b3, A, 0, n_nodes);

    k_pool<<<n_graphs, 128, 0, stream>>>(A, batch, Wlin, blin, out, n_nodes);
}